// Round 8
// baseline (237.767 us; speedup 1.0000x reference)
//
#include <hip/hip_runtime.h>
#include <hip/hip_bf16.h>
#include <math.h>

#define B_    16
#define C_    512
#define N_    1024
#define G_    8
#define HEADS 4
#define CH    128
#define EPS   1e-5f

typedef __attribute__((ext_vector_type(8))) short short8;
typedef __attribute__((ext_vector_type(4))) float f32x4;
typedef __attribute__((ext_vector_type(16))) float f32x16;
typedef __attribute__((ext_vector_type(4))) int i32x4;

__device__ __forceinline__ unsigned short f2bf(float f) {
  union { float f; unsigned int i; } x; x.f = f;
  unsigned int r = x.i + 0x7FFFu + ((x.i >> 16) & 1u);
  return (unsigned short)(r >> 16);
}

// ---------------- GroupNorm partial sums: 4 chunks per (b,g), deterministic ----------------
__global__ __launch_bounds__(256) void gn_part(const float* __restrict__ x,
                                               float2* __restrict__ psum) {
  int blk = blockIdx.x;  // bg*4 + chunk, 0..511
  const float4* p4 = (const float4*)(x + (size_t)blk * 16384);
  float s = 0.f, ss = 0.f;
  for (int i = threadIdx.x; i < 4096; i += 256) {
    float4 v = p4[i];
    s  += v.x + v.y + v.z + v.w;
    ss += v.x * v.x + v.y * v.y + v.z * v.z + v.w * v.w;
  }
  for (int o = 32; o; o >>= 1) { s += __shfl_down(s, o); ss += __shfl_down(ss, o); }
  __shared__ float ls[4], lss[4];
  int wid = threadIdx.x >> 6, lane = threadIdx.x & 63;
  if (lane == 0) { ls[wid] = s; lss[wid] = ss; }
  __syncthreads();
  if (threadIdx.x == 0) {
    float2 r;
    r.x = (ls[0] + ls[1]) + (ls[2] + ls[3]);
    r.y = (lss[0] + lss[1]) + (lss[2] + lss[3]);
    psum[blk] = r;
  }
}

// ---------------- weight conversion fp32 -> bf16 + packed qk bias ----------------
__global__ __launch_bounds__(256) void conv_w(const float* __restrict__ q, const float* __restrict__ k,
                                              const float* __restrict__ v, const float* __restrict__ p,
                                              const float* __restrict__ qb, const float* __restrict__ kb,
                                              unsigned short* __restrict__ dst,
                                              float* __restrict__ qkb) {
  const int n = C_ * C_;
  int i = blockIdx.x * 256 + threadIdx.x;
  if (i < n) {
    dst[i]         = f2bf(q[i]);
    dst[n + i]     = f2bf(k[i]);
    dst[2 * n + i] = f2bf(v[i]);
    dst[3 * n + i] = f2bf(p[i]);
  }
  if (i < 1024) qkb[i] = (i < 512) ? qb[i] : kb[i - 512];
}

// ---------------- GroupNorm apply + transpose -> hT (B, N, C) bf16 ----------------
__global__ __launch_bounds__(256) void gn_apply(const float* __restrict__ x,
                                                const float2* __restrict__ psum,
                                                const float* __restrict__ gw,
                                                const float* __restrict__ gb,
                                                unsigned short* __restrict__ hT) {
  __shared__ float T[64][65];
  int b = blockIdx.z, c0 = blockIdx.y * 64, n0 = blockIdx.x * 64;
  int bg = b * G_ + (c0 >> 6);
  float2 p0 = psum[bg * 4 + 0], p1 = psum[bg * 4 + 1];
  float2 p2 = psum[bg * 4 + 2], p3 = psum[bg * 4 + 3];
  const float inv = 1.f / ((C_ / G_) * N_);
  float mean = ((p0.x + p1.x) + (p2.x + p3.x)) * inv;
  float var  = ((p0.y + p1.y) + (p2.y + p3.y)) * inv - mean * mean;
  float rstd = rsqrtf(var + EPS);
  int t = threadIdx.x;
  for (int it = 0; it < 4; it++) {
    int L = it * 256 + t;
    int cc = L >> 4, nf = L & 15;
    float4 v = *(const float4*)&x[((size_t)b * C_ + c0 + cc) * N_ + n0 + nf * 4];
    float sw = gw[c0 + cc] * rstd, sb = gb[c0 + cc] - mean * sw;
    T[cc][nf * 4 + 0] = v.x * sw + sb;
    T[cc][nf * 4 + 1] = v.y * sw + sb;
    T[cc][nf * 4 + 2] = v.z * sw + sb;
    T[cc][nf * 4 + 3] = v.w * sw + sb;
  }
  __syncthreads();
  for (int it = 0; it < 4; it++) {
    int L = it * 256 + t;
    int nn = L >> 4, cv = L & 15;
    ushort4 o;
    o.x = f2bf(T[cv * 4 + 0][nn]);
    o.y = f2bf(T[cv * 4 + 1][nn]);
    o.z = f2bf(T[cv * 4 + 2][nn]);
    o.w = f2bf(T[cv * 4 + 3][nn]);
    *(ushort4*)&hT[((size_t)b * N_ + n0 + nn) * C_ + c0 + cv * 4] = o;
  }
}

// ---------------- TN GEMM (m97-structure), XCD-grouped by batch ----------------
template <bool OUT_BF16, bool BIAS_I, bool RESID>
__global__ __launch_bounds__(256) void gemm_tn(const unsigned short* __restrict__ A,
                                               const unsigned short* __restrict__ Bt,
                                               const float* __restrict__ bias,
                                               const float* __restrict__ resid,
                                               void* __restrict__ out,
                                               int Ncols, int K,
                                               long aBS, long bBS, long oBS) {
  __shared__ __align__(16) unsigned short As[128 * 64];
  __shared__ __align__(16) unsigned short Bs[128 * 64];
  const int lin = blockIdx.x;
  const int b = (lin & 7) * 2 + ((lin >> 3) & 1);
  const int rest = lin >> 4;
  const int bx = rest & 7, by = rest >> 3;
  const int i0 = by * 128, j0 = bx * 128;
  const unsigned short* Ab = A + (size_t)b * aBS + (size_t)i0 * K;
  const unsigned short* Bb = Bt + (size_t)b * bBS + (size_t)j0 * K;
  const int t = threadIdx.x, w = t >> 6, l = t & 63;
  const int wi = (w >> 1) * 64, wj = (w & 1) * 64;
  const int lr = l & 15, lk = (l >> 4) * 8;
  const int srow = l >> 3, scol = (l & 7) * 8;

  f32x4 acc[4][4];
  const f32x4 zf = {0.f, 0.f, 0.f, 0.f};
#pragma unroll
  for (int m = 0; m < 4; m++)
#pragma unroll
    for (int n = 0; n < 4; n++) acc[m][n] = zf;

  for (int kt = 0; kt < K; kt += 64) {
    __syncthreads();
#pragma unroll
    for (int i = 0; i < 4; i++) {
      int seg = w * 4 + i;
      int row = seg * 8 + srow;
      __builtin_amdgcn_global_load_lds(
          (const __attribute__((address_space(1))) void*)&Ab[(size_t)row * K + kt + scol],
          (__attribute__((address_space(3))) void*)&As[seg * 512], 16, 0, 0);
      __builtin_amdgcn_global_load_lds(
          (const __attribute__((address_space(1))) void*)&Bb[(size_t)row * K + kt + scol],
          (__attribute__((address_space(3))) void*)&Bs[seg * 512], 16, 0, 0);
    }
    __syncthreads();
#pragma unroll
    for (int ks = 0; ks < 64; ks += 32) {
      short8 af[4], bf[4];
#pragma unroll
      for (int m = 0; m < 4; m++) af[m] = *(const short8*)&As[(wi + m * 16 + lr) * 64 + ks + lk];
#pragma unroll
      for (int n = 0; n < 4; n++) bf[n] = *(const short8*)&Bs[(wj + n * 16 + lr) * 64 + ks + lk];
#pragma unroll
      for (int m = 0; m < 4; m++)
#pragma unroll
        for (int n = 0; n < 4; n++)
          acc[m][n] = __builtin_amdgcn_mfma_f32_16x16x32_bf16(af[m], bf[n], acc[m][n], 0, 0, 0);
    }
  }

  int rbase = (l >> 4) * 4;
#pragma unroll
  for (int m = 0; m < 4; m++) {
    int ig = i0 + wi + m * 16 + rbase;
#pragma unroll
    for (int n = 0; n < 4; n++) {
      int jg = j0 + wj + n * 16 + lr;
#pragma unroll
      for (int r = 0; r < 4; r++) {
        float vv = acc[m][n][r];
        vv += BIAS_I ? bias[ig + r] : bias[jg];
        size_t oidx = (size_t)b * oBS + (size_t)(ig + r) * Ncols + jg;
        if (RESID) vv += resid[oidx];
        if (OUT_BF16) ((unsigned short*)out)[oidx] = f2bf(vv);
        else ((float*)out)[oidx] = vv;
      }
    }
  }
}

// ---------------- fused flash attention: 4 waves share 32 q; c-split across waves ----------
// Each wave: full QK^T + softmax (duplicated, deterministic); PV + output for its c-quarter.
// KVBLK=32, K/V double-buffered (32 KiB LDS) -> 4 blocks/CU, 16 waves/CU.
// qkT: (B, N, 1024) bf16 (q cols 0..511, k cols 512..1023); v: (B, C, N) bf16; out aoT: (B, N, C) bf16
__global__ __launch_bounds__(256, 4) void attn_kernel(const unsigned short* __restrict__ qkT,
                                                      const unsigned short* __restrict__ v,
                                                      unsigned short* __restrict__ aoT) {
  __shared__ __align__(16) unsigned short Ks[2][32 * 128];
  __shared__ __align__(16) unsigned short Vs[2][128 * 32];
  const int t = threadIdx.x, w = t >> 6, l = t & 63;   // w = c-quarter (0..3)
  const int h = l >> 5, l31 = l & 31;
  const int lin = blockIdx.x;
  const int bh = (lin & 7) * 8 + ((lin >> 3) & 7);  // XCD-grouped: all q-tiles of bh on one XCD
  const int qt = lin >> 6;                          // 0..31
  const int b = bh >> 2, hd = bh & 3, c0h = hd * CH;
  const int qg = qt * 32 + l31;                     // shared q-rows across all 4 waves
  const float sc2 = 0.08838834764831845f * 1.4426950408889634f;  // scale * log2(e)
  const float THRRAW = 11.5f / sc2;                              // defer-max threshold

  // Q fragments (MFMA B-operand): identical in all 4 waves
  short8 qf[8];
  const unsigned short* qrow = qkT + ((size_t)b * N_ + qg) * 1024 + c0h;
#pragma unroll
  for (int kc = 0; kc < 8; kc++) qf[kc] = *(const short8*)&qrow[kc * 16 + h * 8];

  f32x16 o = (f32x16)(0.f);   // this wave's c-quarter accumulator (32 q x 32 c)
  float m = -INFINITY, lsum = 0.f;

  // hoisted staging source pointers (pre-swizzled; advance one tile per stage call)
  const unsigned short* ksrc[2];
  const unsigned short* vsrc[2];
#pragma unroll
  for (int i = 0; i < 2; i++) {
    int seg = w * 2 + i;  // 0..7
    int rowK = seg * 4 + (l >> 4);          // 0..31
    int gcK = (l & 15) ^ (rowK & 15);       // proven pair (r5)
    ksrc[i] = qkT + ((size_t)b * N_ + rowK) * 1024 + 512 + c0h + gcK * 8;
    int rowV = seg * 16 + (l >> 2);         // 0..127
    int gcV = (l & 3) ^ ((rowV >> 1) & 3);  // proven pair (r5)
    vsrc[i] = v + ((size_t)b * C_ + c0h + rowV) * N_ + gcV * 8;
  }

  auto stage = [&](int cur) {
    unsigned short* KsD = &Ks[cur][0];
    unsigned short* VsD = &Vs[cur][0];
#pragma unroll
    for (int i = 0; i < 2; i++) {
      int seg = w * 2 + i;
      __builtin_amdgcn_global_load_lds((const __attribute__((address_space(1))) void*)ksrc[i],
                                       (__attribute__((address_space(3))) void*)&KsD[seg * 512],
                                       16, 0, 0);
      ksrc[i] += 32 * 1024;  // next 32 kv rows
      __builtin_amdgcn_global_load_lds((const __attribute__((address_space(1))) void*)vsrc[i],
                                       (__attribute__((address_space(3))) void*)&VsD[seg * 512],
                                       16, 0, 0);
      vsrc[i] += 32;  // next 32 kv cols
    }
  };

  stage(0);

  // LDS read bases (short units), proven pairs from r5
  const int kbase = l31 * 128 + (h ^ (l31 & 15)) * 8;  // K index = kbase ^ (kc*16)
  const int vbase = l31 * 32 + (h ^ ((l31 >> 1) & 3)) * 8;  // V index = cq*1024 + (vbase ^ (g*16))

  for (int tt = 0; tt < 32; tt++) {
    int cur = tt & 1;
    __syncthreads();  // staged tile ready; prev-tile reads done
    if (tt < 31) stage(cur ^ 1);

    // ---- QK^T (swapped): S^T[kv][q] = sum_c K[kv][c] * Q[q][c] ----
    f32x16 st = (f32x16)(0.f);
    const unsigned short* KsB = &Ks[cur][0];
    __builtin_amdgcn_s_setprio(1);
#pragma unroll
    for (int kc = 0; kc < 8; kc++) {
      short8 kf = *(const short8*)&KsB[kbase ^ (kc * 16)];
      st = __builtin_amdgcn_mfma_f32_32x32x16_bf16(kf, qf[kc], st, 0, 0, 0);
    }
    __builtin_amdgcn_s_setprio(0);

    // ---- in-register online softmax (lane holds 16 kv for q=l31; lane^32 the other 16) ----
    float tr[8];
#pragma unroll
    for (int r = 0; r < 8; r++) tr[r] = fmaxf(st[r], st[r + 8]);
#pragma unroll
    for (int s = 4; s >= 1; s >>= 1)
#pragma unroll
      for (int r = 0; r < s; r++) tr[r] = fmaxf(tr[r], tr[r + s]);
    float pmax = fmaxf(tr[0], __shfl_xor(tr[0], 32));

    bool skip = __all(pmax <= m + THRRAW);
    float mnew = skip ? m : fmaxf(m, pmax);
    float alpha = skip ? 1.f : exp2f((m - mnew) * sc2);
    float mb = mnew * sc2;
    m = mnew;

    float psg[2];
    short8 pf[2];
#pragma unroll
    for (int g = 0; g < 2; g++) {
      const int e0 = g * 8;
      float p0 = exp2f(fmaf(st[e0 + 0], sc2, -mb)), p1 = exp2f(fmaf(st[e0 + 1], sc2, -mb));
      float p2 = exp2f(fmaf(st[e0 + 2], sc2, -mb)), p3 = exp2f(fmaf(st[e0 + 3], sc2, -mb));
      float p4 = exp2f(fmaf(st[e0 + 4], sc2, -mb)), p5 = exp2f(fmaf(st[e0 + 5], sc2, -mb));
      float p6 = exp2f(fmaf(st[e0 + 6], sc2, -mb)), p7 = exp2f(fmaf(st[e0 + 7], sc2, -mb));
      psg[g] = ((p0 + p1) + (p2 + p3)) + ((p4 + p5) + (p6 + p7));
      unsigned int x, x2, y, y2;
      asm("v_cvt_pk_bf16_f32 %0, %1, %2" : "=v"(x)  : "v"(p0), "v"(p1));
      asm("v_cvt_pk_bf16_f32 %0, %1, %2" : "=v"(x2) : "v"(p2), "v"(p3));
      asm("v_cvt_pk_bf16_f32 %0, %1, %2" : "=v"(y)  : "v"(p4), "v"(p5));
      asm("v_cvt_pk_bf16_f32 %0, %1, %2" : "=v"(y2) : "v"(p6), "v"(p7));
      asm("v_permlane32_swap_b32 %0, %1" : "+v"(x), "+v"(y));
      asm("v_permlane32_swap_b32 %0, %1" : "+v"(x2), "+v"(y2));
      i32x4 pwv = {(int)x, (int)x2, (int)y, (int)y2};
      pf[g] = __builtin_bit_cast(short8, pwv);
    }
    float ps = psg[0] + psg[1];
    ps += __shfl_xor(ps, 32);
    lsum = lsum * alpha + ps;

    if (!skip) {
#pragma unroll
      for (int r = 0; r < 16; r++) o[r] *= alpha;
    }

    // ---- PV (c-quarter cq = w): O^T[c][q] += sum_kv V[c][kv] * P[q][kv] ----
    const unsigned short* VsB = &Vs[cur][0];
    __builtin_amdgcn_s_setprio(1);
#pragma unroll
    for (int g = 0; g < 2; g++) {
      short8 vf = *(const short8*)&VsB[w * 1024 + (vbase ^ (g * 16))];
      o = __builtin_amdgcn_mfma_f32_32x32x16_bf16(vf, pf[g], o, 0, 0, 0);
    }
    __builtin_amdgcn_s_setprio(0);
  }

  float rn = 1.f / lsum;
  unsigned short* orow = aoT + ((size_t)b * N_ + qg) * C_ + c0h;
#pragma unroll
  for (int u = 0; u < 4; u++) {
    ushort4 ov;
    ov.x = f2bf(o[u * 4 + 0] * rn);
    ov.y = f2bf(o[u * 4 + 1] * rn);
    ov.z = f2bf(o[u * 4 + 2] * rn);
    ov.w = f2bf(o[u * 4 + 3] * rn);
    *(ushort4*)&orow[w * 32 + u * 8 + h * 4] = ov;
  }
}

extern "C" void kernel_launch(void* const* d_in, const int* in_sizes, int n_in,
                              void* d_out, int out_size, void* d_ws, size_t ws_size,
                              hipStream_t stream) {
  const float* x  = (const float*)d_in[0];
  const float* nw = (const float*)d_in[1];
  const float* nb = (const float*)d_in[2];
  const float* qw = (const float*)d_in[3];
  const float* qb = (const float*)d_in[4];
  const float* kw = (const float*)d_in[5];
  const float* kb = (const float*)d_in[6];
  const float* vw = (const float*)d_in[7];
  const float* vb = (const float*)d_in[8];
  const float* pw = (const float*)d_in[9];
  const float* pb = (const float*)d_in[10];

  char* ws = (char*)d_ws;
  unsigned short* wbf  = (unsigned short*)ws;                  // 4 x 512*512 bf16 (q,k,v,p)
  float2*         psum = (float2*)(ws + 0x200000);             // 512 float2 partial sums
  float*          qkb  = (float*)(ws + 0x201000);              // 1024 floats packed q,k bias
  unsigned short* hT   = (unsigned short*)(ws + 0x202000);     // 16 MiB (B,N,C)
  unsigned short* qkT  = (unsigned short*)(ws + 0x1202000);    // 32 MiB (B,N,1024)
  unsigned short* vv   = (unsigned short*)(ws + 0x3202000);    // 16 MiB (B,C,N)
  unsigned short* aoT  = hT;                                   // reuse after h consumed

  const long NC = (long)N_ * C_;
  const int n_w = C_ * C_;

  gn_part<<<512, 256, 0, stream>>>(x, psum);
  conv_w<<<n_w / 256, 256, 0, stream>>>(qw, kw, vw, pw, qb, kb, wbf, qkb);
  gn_apply<<<dim3(N_ / 64, C_ / 64, B_), 256, 0, stream>>>(x, psum, nw, nb, hT);

  // fused Q+K: qkT[b][n][j] = sum_c hT[n][c] * wbf[j][c] + qkb[j]   (grid 16*8*8 = 1024)
  gemm_tn<true, false, false><<<dim3(1024), 256, 0, stream>>>(
      hT, wbf, qkb, nullptr, qkT, 1024, C_, NC, 0, (long)N_ * 1024);
  // v: vv[b][o][n] = sum_c vw[o][c] hT[n][c] + vb[o]                (grid 16*8*4 = 512)
  gemm_tn<true, true, false><<<dim3(512), 256, 0, stream>>>(
      wbf + 2 * n_w, hT, vb, nullptr, vv, N_, C_, 0, NC, NC);

  attn_kernel<<<dim3(2048), 256, 0, stream>>>(qkT, vv, aoT);

  // p: out[b][o][n] = sum_c pw[o][c] ao[c][n] + pb[o] + x           (grid 16*8*4 = 512)
  gemm_tn<false, true, true><<<dim3(512), 256, 0, stream>>>(
      wbf + 3 * n_w, aoT, pb, x, d_out, N_, C_, 0, NC, NC);
}

// Round 9
// 143.837 us; speedup vs baseline: 1.6530x; 1.6530x over previous
//
#include <hip/hip_runtime.h>
#include <hip/hip_bf16.h>
#include <math.h>

#define B_    16
#define C_    512
#define N_    1024
#define G_    8
#define HEADS 4
#define CH    128
#define EPS   1e-5f

typedef __attribute__((ext_vector_type(8))) short short8;
typedef __attribute__((ext_vector_type(4))) float f32x4;
typedef __attribute__((ext_vector_type(16))) float f32x16;
typedef __attribute__((ext_vector_type(4))) int i32x4;

__device__ __forceinline__ unsigned short f2bf(float f) {
  union { float f; unsigned int i; } x; x.f = f;
  unsigned int r = x.i + 0x7FFFu + ((x.i >> 16) & 1u);
  return (unsigned short)(r >> 16);
}

// ---------------- GroupNorm partial sums: 4 chunks per (b,g), deterministic ----------------
__global__ __launch_bounds__(256) void gn_part(const float* __restrict__ x,
                                               float2* __restrict__ psum) {
  int blk = blockIdx.x;  // bg*4 + chunk, 0..511
  const float4* p4 = (const float4*)(x + (size_t)blk * 16384);
  float s = 0.f, ss = 0.f;
  for (int i = threadIdx.x; i < 4096; i += 256) {
    float4 v = p4[i];
    s  += v.x + v.y + v.z + v.w;
    ss += v.x * v.x + v.y * v.y + v.z * v.z + v.w * v.w;
  }
  for (int o = 32; o; o >>= 1) { s += __shfl_down(s, o); ss += __shfl_down(ss, o); }
  __shared__ float ls[4], lss[4];
  int wid = threadIdx.x >> 6, lane = threadIdx.x & 63;
  if (lane == 0) { ls[wid] = s; lss[wid] = ss; }
  __syncthreads();
  if (threadIdx.x == 0) {
    float2 r;
    r.x = (ls[0] + ls[1]) + (ls[2] + ls[3]);
    r.y = (lss[0] + lss[1]) + (lss[2] + lss[3]);
    psum[blk] = r;
  }
}

// ---------------- weight conversion fp32 -> bf16 + packed qk bias ----------------
__global__ __launch_bounds__(256) void conv_w(const float* __restrict__ q, const float* __restrict__ k,
                                              const float* __restrict__ v, const float* __restrict__ p,
                                              const float* __restrict__ qb, const float* __restrict__ kb,
                                              unsigned short* __restrict__ dst,
                                              float* __restrict__ qkb) {
  const int n = C_ * C_;
  int i = blockIdx.x * 256 + threadIdx.x;
  if (i < n) {
    dst[i]         = f2bf(q[i]);
    dst[n + i]     = f2bf(k[i]);
    dst[2 * n + i] = f2bf(v[i]);
    dst[3 * n + i] = f2bf(p[i]);
  }
  if (i < 1024) qkb[i] = (i < 512) ? qb[i] : kb[i - 512];
}

// ---------------- GroupNorm apply + transpose -> hT (B, N, C) bf16 ----------------
__global__ __launch_bounds__(256) void gn_apply(const float* __restrict__ x,
                                                const float2* __restrict__ psum,
                                                const float* __restrict__ gw,
                                                const float* __restrict__ gb,
                                                unsigned short* __restrict__ hT) {
  __shared__ float T[64][65];
  int b = blockIdx.z, c0 = blockIdx.y * 64, n0 = blockIdx.x * 64;
  int bg = b * G_ + (c0 >> 6);
  float2 p0 = psum[bg * 4 + 0], p1 = psum[bg * 4 + 1];
  float2 p2 = psum[bg * 4 + 2], p3 = psum[bg * 4 + 3];
  const float inv = 1.f / ((C_ / G_) * N_);
  float mean = ((p0.x + p1.x) + (p2.x + p3.x)) * inv;
  float var  = ((p0.y + p1.y) + (p2.y + p3.y)) * inv - mean * mean;
  float rstd = rsqrtf(var + EPS);
  int t = threadIdx.x;
  for (int it = 0; it < 4; it++) {
    int L = it * 256 + t;
    int cc = L >> 4, nf = L & 15;
    float4 v = *(const float4*)&x[((size_t)b * C_ + c0 + cc) * N_ + n0 + nf * 4];
    float sw = gw[c0 + cc] * rstd, sb = gb[c0 + cc] - mean * sw;
    T[cc][nf * 4 + 0] = v.x * sw + sb;
    T[cc][nf * 4 + 1] = v.y * sw + sb;
    T[cc][nf * 4 + 2] = v.z * sw + sb;
    T[cc][nf * 4 + 3] = v.w * sw + sb;
  }
  __syncthreads();
  for (int it = 0; it < 4; it++) {
    int L = it * 256 + t;
    int nn = L >> 4, cv = L & 15;
    ushort4 o;
    o.x = f2bf(T[cv * 4 + 0][nn]);
    o.y = f2bf(T[cv * 4 + 1][nn]);
    o.z = f2bf(T[cv * 4 + 2][nn]);
    o.w = f2bf(T[cv * 4 + 3][nn]);
    *(ushort4*)&hT[((size_t)b * N_ + n0 + nn) * C_ + c0 + cv * 4] = o;
  }
}

// ---------------- TN GEMM (m97-structure), XCD-grouped by batch ----------------
template <bool OUT_BF16, bool BIAS_I, bool RESID>
__global__ __launch_bounds__(256) void gemm_tn(const unsigned short* __restrict__ A,
                                               const unsigned short* __restrict__ Bt,
                                               const float* __restrict__ bias,
                                               const float* __restrict__ resid,
                                               void* __restrict__ out,
                                               int Ncols, int K,
                                               long aBS, long bBS, long oBS) {
  __shared__ __align__(16) unsigned short As[128 * 64];
  __shared__ __align__(16) unsigned short Bs[128 * 64];
  const int lin = blockIdx.x;
  const int b = (lin & 7) * 2 + ((lin >> 3) & 1);
  const int rest = lin >> 4;
  const int bx = rest & 7, by = rest >> 3;
  const int i0 = by * 128, j0 = bx * 128;
  const unsigned short* Ab = A + (size_t)b * aBS + (size_t)i0 * K;
  const unsigned short* Bb = Bt + (size_t)b * bBS + (size_t)j0 * K;
  const int t = threadIdx.x, w = t >> 6, l = t & 63;
  const int wi = (w >> 1) * 64, wj = (w & 1) * 64;
  const int lr = l & 15, lk = (l >> 4) * 8;
  const int srow = l >> 3, scol = (l & 7) * 8;

  f32x4 acc[4][4];
  const f32x4 zf = {0.f, 0.f, 0.f, 0.f};
#pragma unroll
  for (int m = 0; m < 4; m++)
#pragma unroll
    for (int n = 0; n < 4; n++) acc[m][n] = zf;

  for (int kt = 0; kt < K; kt += 64) {
    __syncthreads();
#pragma unroll
    for (int i = 0; i < 4; i++) {
      int seg = w * 4 + i;
      int row = seg * 8 + srow;
      __builtin_amdgcn_global_load_lds(
          (const __attribute__((address_space(1))) void*)&Ab[(size_t)row * K + kt + scol],
          (__attribute__((address_space(3))) void*)&As[seg * 512], 16, 0, 0);
      __builtin_amdgcn_global_load_lds(
          (const __attribute__((address_space(1))) void*)&Bb[(size_t)row * K + kt + scol],
          (__attribute__((address_space(3))) void*)&Bs[seg * 512], 16, 0, 0);
    }
    __syncthreads();
#pragma unroll
    for (int ks = 0; ks < 64; ks += 32) {
      short8 af[4], bf[4];
#pragma unroll
      for (int m = 0; m < 4; m++) af[m] = *(const short8*)&As[(wi + m * 16 + lr) * 64 + ks + lk];
#pragma unroll
      for (int n = 0; n < 4; n++) bf[n] = *(const short8*)&Bs[(wj + n * 16 + lr) * 64 + ks + lk];
#pragma unroll
      for (int m = 0; m < 4; m++)
#pragma unroll
        for (int n = 0; n < 4; n++)
          acc[m][n] = __builtin_amdgcn_mfma_f32_16x16x32_bf16(af[m], bf[n], acc[m][n], 0, 0, 0);
    }
  }

  int rbase = (l >> 4) * 4;
#pragma unroll
  for (int m = 0; m < 4; m++) {
    int ig = i0 + wi + m * 16 + rbase;
#pragma unroll
    for (int n = 0; n < 4; n++) {
      int jg = j0 + wj + n * 16 + lr;
#pragma unroll
      for (int r = 0; r < 4; r++) {
        float vv = acc[m][n][r];
        vv += BIAS_I ? bias[ig + r] : bias[jg];
        size_t oidx = (size_t)b * oBS + (size_t)(ig + r) * Ncols + jg;
        if (RESID) vv += resid[oidx];
        if (OUT_BF16) ((unsigned short*)out)[oidx] = f2bf(vv);
        else ((float*)out)[oidx] = vv;
      }
    }
  }
}

// ---------------- fused flash attention: 4 waves, KVBLK=64, softmax interleaved into QK ----
// qkT: (B, N, 1024) bf16 (q cols 0..511, k cols 512..1023); v: (B, C, N) bf16; out aoT: (B, N, C) bf16
__global__ __launch_bounds__(256, 2) void attn_kernel(const unsigned short* __restrict__ qkT,
                                                      const unsigned short* __restrict__ v,
                                                      unsigned short* __restrict__ aoT) {
  // K: 2 bufs [64 kv][128 c] (16 KiB each); V: 3 bufs [128 c][64 kv] (16 KiB each) => 80 KiB
  __shared__ __align__(16) unsigned short Ks[2][64 * 128];
  __shared__ __align__(16) unsigned short Vs[3][128 * 64];
  const int t = threadIdx.x, w = t >> 6, l = t & 63;
  const int h = l >> 5, l31 = l & 31, l7 = l & 7;
  const int lin = blockIdx.x;
  const int bh = (lin & 7) * 8 + ((lin >> 3) & 7);  // XCD-grouped: all q-tiles of bh on one XCD
  const int qt = lin >> 6;
  const int b = bh >> 2, hd = bh & 3, c0h = hd * CH;
  const int qg = qt * 128 + w * 32 + l31;
  const float sc2 = 0.08838834764831845f * 1.4426950408889634f;  // scale * log2(e)
  const float THRRAW = 11.5f / sc2;                              // defer-max threshold

  // Q fragments (MFMA B-operand)
  short8 qf[8];
  const unsigned short* qrow = qkT + ((size_t)b * N_ + qg) * 1024 + c0h;
#pragma unroll
  for (int kc = 0; kc < 8; kc++) qf[kc] = *(const short8*)&qrow[kc * 16 + h * 8];

  f32x16 o[4];
#pragma unroll
  for (int ct = 0; ct < 4; ct++) o[ct] = (f32x16)(0.f);
  float m = -INFINITY, lsum = 0.f;

  // hoisted pre-swizzled staging source pointers (advance one 64-kv tile per stage call)
  const unsigned short* ksrcp[4];
  const unsigned short* vsrcp[4];
#pragma unroll
  for (int i = 0; i < 4; i++) {
    int seg = w * 4 + i;               // 0..15
    int rowK = seg * 4 + (l >> 4);     // 0..63
    int gcK = (l & 15) ^ (rowK & 7);
    ksrcp[i] = qkT + ((size_t)b * N_ + rowK) * 1024 + 512 + c0h + gcK * 8;
    int rowV = seg * 8 + (l >> 3);     // 0..127
    int gcV = (l & 7) ^ (rowV & 7);
    vsrcp[i] = v + ((size_t)b * C_ + c0h + rowV) * N_ + gcV * 8;
  }
  auto stage = [&](int kbuf, int vbuf) {
#pragma unroll
    for (int i = 0; i < 4; i++) {
      int seg = w * 4 + i;
      __builtin_amdgcn_global_load_lds((const __attribute__((address_space(1))) void*)ksrcp[i],
                                       (__attribute__((address_space(3))) void*)&Ks[kbuf][seg * 512],
                                       16, 0, 0);
      ksrcp[i] += (size_t)64 * 1024;
      __builtin_amdgcn_global_load_lds((const __attribute__((address_space(1))) void*)vsrcp[i],
                                       (__attribute__((address_space(3))) void*)&Vs[vbuf][seg * 512],
                                       16, 0, 0);
      vsrcp[i] += 64;
    }
  };

  // prologue: tiles 0 and 1
  stage(0, 0);
  stage(1, 1);
  __syncthreads();  // tiles 0,1 resident

  // QK^T(0): S^T[kv][q] = sum_c K[kv][c] * Q[q][c]
  f32x16 st0 = (f32x16)(0.f), st1 = (f32x16)(0.f);
  {
    const unsigned short* KsB = &Ks[0][0];
#pragma unroll
    for (int kc = 0; kc < 8; kc++) {
      short8 kf0 = *(const short8*)&KsB[l31 * 128 + (((2 * kc + h) ^ l7) * 8)];
      short8 kf1 = *(const short8*)&KsB[(32 + l31) * 128 + (((2 * kc + h) ^ l7) * 8)];
      st0 = __builtin_amdgcn_mfma_f32_32x32x16_bf16(kf0, qf[kc], st0, 0, 0, 0);
      st1 = __builtin_amdgcn_mfma_f32_32x32x16_bf16(kf1, qf[kc], st1, 0, 0, 0);
    }
  }
  __syncthreads();  // all waves done reading Ks[0] (iter 0 restages it)

  for (int tt = 0; tt < 15; tt++) {
    // stage tile tt+2: K into Ks[tt&1], V into Vs[(tt+2)%3]
    if (tt < 14) stage(tt & 1, (tt + 2) % 3);

    const unsigned short* KsN = &Ks[(tt + 1) & 1][0];
    const unsigned short* VsB = &Vs[tt % 3][0];
    f32x16 nst0 = (f32x16)(0.f), nst1 = (f32x16)(0.f);

    // ---- QK(tt+1) chunk 1 (kc 0..3) — independent of softmax(tt) ----
#pragma unroll
    for (int kc = 0; kc < 4; kc++) {
      short8 kf0 = *(const short8*)&KsN[l31 * 128 + (((2 * kc + h) ^ l7) * 8)];
      short8 kf1 = *(const short8*)&KsN[(32 + l31) * 128 + (((2 * kc + h) ^ l7) * 8)];
      nst0 = __builtin_amdgcn_mfma_f32_32x32x16_bf16(kf0, qf[kc], nst0, 0, 0, 0);
      nst1 = __builtin_amdgcn_mfma_f32_32x32x16_bf16(kf1, qf[kc], nst1, 0, 0, 0);
    }

    // ---- softmax(tt) part A: max tree + cross-half + alpha (hidden under QK MFMA) ----
    float tr[16];
#pragma unroll
    for (int r = 0; r < 16; r++) tr[r] = fmaxf(st0[r], st1[r]);
#pragma unroll
    for (int s = 8; s >= 1; s >>= 1)
#pragma unroll
      for (int r = 0; r < s; r++) tr[r] = fmaxf(tr[r], tr[r + s]);
    float px0 = tr[0], px1 = tr[0];
    asm volatile("v_permlane32_swap_b32 %0, %1" : "+v"(px0), "+v"(px1));
    float pmax = fmaxf(px0, px1);

    bool skip = __all(pmax <= m + THRRAW);
    float mnew = skip ? m : fmaxf(m, pmax);
    float alpha = skip ? 1.f : exp2f((m - mnew) * sc2);
    float mb = mnew * sc2;
    m = mnew;

    // ---- QK(tt+1) chunk 2 (kc 4..7) ----
#pragma unroll
    for (int kc = 4; kc < 8; kc++) {
      short8 kf0 = *(const short8*)&KsN[l31 * 128 + (((2 * kc + h) ^ l7) * 8)];
      short8 kf1 = *(const short8*)&KsN[(32 + l31) * 128 + (((2 * kc + h) ^ l7) * 8)];
      nst0 = __builtin_amdgcn_mfma_f32_32x32x16_bf16(kf0, qf[kc], nst0, 0, 0, 0);
      nst1 = __builtin_amdgcn_mfma_f32_32x32x16_bf16(kf1, qf[kc], nst1, 0, 0, 0);
    }

    // ---- softmax(tt) part B: exp + pack + sums + rescale (hidden under QK MFMA) ----
    float psg[4];
    short8 pf[4];
#pragma unroll
    for (int g = 0; g < 4; g++) {
      const int e0 = (g & 1) * 8;
      float p0, p1, p2, p3, p4, p5, p6, p7;
      if (g < 2) {
        p0 = exp2f(fmaf(st0[e0 + 0], sc2, -mb)); p1 = exp2f(fmaf(st0[e0 + 1], sc2, -mb));
        p2 = exp2f(fmaf(st0[e0 + 2], sc2, -mb)); p3 = exp2f(fmaf(st0[e0 + 3], sc2, -mb));
        p4 = exp2f(fmaf(st0[e0 + 4], sc2, -mb)); p5 = exp2f(fmaf(st0[e0 + 5], sc2, -mb));
        p6 = exp2f(fmaf(st0[e0 + 6], sc2, -mb)); p7 = exp2f(fmaf(st0[e0 + 7], sc2, -mb));
      } else {
        p0 = exp2f(fmaf(st1[e0 + 0], sc2, -mb)); p1 = exp2f(fmaf(st1[e0 + 1], sc2, -mb));
        p2 = exp2f(fmaf(st1[e0 + 2], sc2, -mb)); p3 = exp2f(fmaf(st1[e0 + 3], sc2, -mb));
        p4 = exp2f(fmaf(st1[e0 + 4], sc2, -mb)); p5 = exp2f(fmaf(st1[e0 + 5], sc2, -mb));
        p6 = exp2f(fmaf(st1[e0 + 6], sc2, -mb)); p7 = exp2f(fmaf(st1[e0 + 7], sc2, -mb));
      }
      psg[g] = ((p0 + p1) + (p2 + p3)) + ((p4 + p5) + (p6 + p7));
      unsigned int x, x2, y, y2;
      asm("v_cvt_pk_bf16_f32 %0, %1, %2" : "=v"(x)  : "v"(p0), "v"(p1));
      asm("v_cvt_pk_bf16_f32 %0, %1, %2" : "=v"(x2) : "v"(p2), "v"(p3));
      asm("v_cvt_pk_bf16_f32 %0, %1, %2" : "=v"(y)  : "v"(p4), "v"(p5));
      asm("v_cvt_pk_bf16_f32 %0, %1, %2" : "=v"(y2) : "v"(p6), "v"(p7));
      asm("v_permlane32_swap_b32 %0, %1" : "+v"(x), "+v"(y));
      asm("v_permlane32_swap_b32 %0, %1" : "+v"(x2), "+v"(y2));
      i32x4 pwv = {(int)x, (int)x2, (int)y, (int)y2};
      pf[g] = __builtin_bit_cast(short8, pwv);
    }
    float ps = (psg[0] + psg[1]) + (psg[2] + psg[3]);
    float s0 = ps, s1 = ps;
    asm volatile("v_permlane32_swap_b32 %0, %1" : "+v"(s0), "+v"(s1));
    ps = s0 + s1;
    lsum = lsum * alpha + ps;

    if (!skip) {
#pragma unroll
      for (int ct = 0; ct < 4; ct++)
#pragma unroll
        for (int r = 0; r < 16; r++) o[ct][r] *= alpha;
    }

    // ---- PV(tt) ----
#pragma unroll
    for (int p = 0; p < 16; p++) {
      int ct = p & 3, g = p >> 2;
      short8 vf = *(const short8*)&VsB[(ct * 32 + l31) * 64 + (((2 * g + h) ^ l7) * 8)];
      o[ct] = __builtin_amdgcn_mfma_f32_32x32x16_bf16(vf, pf[g], o[ct], 0, 0, 0);
    }

    __syncthreads();  // staged tile landed; all reads of overwritten bufs done
    st0 = nst0; st1 = nst1;
  }

  // ---- tail: softmax(15) + PV(15), no further QK/staging ----
  {
    const unsigned short* VsB = &Vs[15 % 3][0];
    float tr[16];
#pragma unroll
    for (int r = 0; r < 16; r++) tr[r] = fmaxf(st0[r], st1[r]);
#pragma unroll
    for (int s = 8; s >= 1; s >>= 1)
#pragma unroll
      for (int r = 0; r < s; r++) tr[r] = fmaxf(tr[r], tr[r + s]);
    float px0 = tr[0], px1 = tr[0];
    asm volatile("v_permlane32_swap_b32 %0, %1" : "+v"(px0), "+v"(px1));
    float pmax = fmaxf(px0, px1);

    bool skip = __all(pmax <= m + THRRAW);
    float mnew = skip ? m : fmaxf(m, pmax);
    float alpha = skip ? 1.f : exp2f((m - mnew) * sc2);
    float mb = mnew * sc2;
    m = mnew;

    float psg[4];
    short8 pf[4];
#pragma unroll
    for (int g = 0; g < 4; g++) {
      const int e0 = (g & 1) * 8;
      float p0, p1, p2, p3, p4, p5, p6, p7;
      if (g < 2) {
        p0 = exp2f(fmaf(st0[e0 + 0], sc2, -mb)); p1 = exp2f(fmaf(st0[e0 + 1], sc2, -mb));
        p2 = exp2f(fmaf(st0[e0 + 2], sc2, -mb)); p3 = exp2f(fmaf(st0[e0 + 3], sc2, -mb));
        p4 = exp2f(fmaf(st0[e0 + 4], sc2, -mb)); p5 = exp2f(fmaf(st0[e0 + 5], sc2, -mb));
        p6 = exp2f(fmaf(st0[e0 + 6], sc2, -mb)); p7 = exp2f(fmaf(st0[e0 + 7], sc2, -mb));
      } else {
        p0 = exp2f(fmaf(st1[e0 + 0], sc2, -mb)); p1 = exp2f(fmaf(st1[e0 + 1], sc2, -mb));
        p2 = exp2f(fmaf(st1[e0 + 2], sc2, -mb)); p3 = exp2f(fmaf(st1[e0 + 3], sc2, -mb));
        p4 = exp2f(fmaf(st1[e0 + 4], sc2, -mb)); p5 = exp2f(fmaf(st1[e0 + 5], sc2, -mb));
        p6 = exp2f(fmaf(st1[e0 + 6], sc2, -mb)); p7 = exp2f(fmaf(st1[e0 + 7], sc2, -mb));
      }
      psg[g] = ((p0 + p1) + (p2 + p3)) + ((p4 + p5) + (p6 + p7));
      unsigned int x, x2, y, y2;
      asm("v_cvt_pk_bf16_f32 %0, %1, %2" : "=v"(x)  : "v"(p0), "v"(p1));
      asm("v_cvt_pk_bf16_f32 %0, %1, %2" : "=v"(x2) : "v"(p2), "v"(p3));
      asm("v_cvt_pk_bf16_f32 %0, %1, %2" : "=v"(y)  : "v"(p4), "v"(p5));
      asm("v_cvt_pk_bf16_f32 %0, %1, %2" : "=v"(y2) : "v"(p6), "v"(p7));
      asm("v_permlane32_swap_b32 %0, %1" : "+v"(x), "+v"(y));
      asm("v_permlane32_swap_b32 %0, %1" : "+v"(x2), "+v"(y2));
      i32x4 pwv = {(int)x, (int)x2, (int)y, (int)y2};
      pf[g] = __builtin_bit_cast(short8, pwv);
    }
    float ps = (psg[0] + psg[1]) + (psg[2] + psg[3]);
    float s0 = ps, s1 = ps;
    asm volatile("v_permlane32_swap_b32 %0, %1" : "+v"(s0), "+v"(s1));
    ps = s0 + s1;
    lsum = lsum * alpha + ps;

    if (!skip) {
#pragma unroll
      for (int ct = 0; ct < 4; ct++)
#pragma unroll
        for (int r = 0; r < 16; r++) o[ct][r] *= alpha;
    }

#pragma unroll
    for (int p = 0; p < 16; p++) {
      int ct = p & 3, g = p >> 2;
      short8 vf = *(const short8*)&VsB[(ct * 32 + l31) * 64 + (((2 * g + h) ^ l7) * 8)];
      o[ct] = __builtin_amdgcn_mfma_f32_32x32x16_bf16(vf, pf[g], o[ct], 0, 0, 0);
    }
  }

  float rn = 1.f / lsum;
  unsigned short* orow = aoT + ((size_t)b * N_ + qg) * C_ + c0h;
#pragma unroll
  for (int ct = 0; ct < 4; ct++)
#pragma unroll
    for (int u = 0; u < 4; u++) {
      ushort4 ov;
      ov.x = f2bf(o[ct][u * 4 + 0] * rn);
      ov.y = f2bf(o[ct][u * 4 + 1] * rn);
      ov.z = f2bf(o[ct][u * 4 + 2] * rn);
      ov.w = f2bf(o[ct][u * 4 + 3] * rn);
      *(ushort4*)&orow[ct * 32 + u * 8 + h * 4] = ov;
    }
}

extern "C" void kernel_launch(void* const* d_in, const int* in_sizes, int n_in,
                              void* d_out, int out_size, void* d_ws, size_t ws_size,
                              hipStream_t stream) {
  const float* x  = (const float*)d_in[0];
  const float* nw = (const float*)d_in[1];
  const float* nb = (const float*)d_in[2];
  const float* qw = (const float*)d_in[3];
  const float* qb = (const float*)d_in[4];
  const float* kw = (const float*)d_in[5];
  const float* kb = (const float*)d_in[6];
  const float* vw = (const float*)d_in[7];
  const float* vb = (const float*)d_in[8];
  const float* pw = (const float*)d_in[9];
  const float* pb = (const float*)d_in[10];

  char* ws = (char*)d_ws;
  unsigned short* wbf  = (unsigned short*)ws;                  // 4 x 512*512 bf16 (q,k,v,p)
  float2*         psum = (float2*)(ws + 0x200000);             // 512 float2 partial sums
  float*          qkb  = (float*)(ws + 0x201000);              // 1024 floats packed q,k bias
  unsigned short* hT   = (unsigned short*)(ws + 0x202000);     // 16 MiB (B,N,C)
  unsigned short* qkT  = (unsigned short*)(ws + 0x1202000);    // 32 MiB (B,N,1024)
  unsigned short* vv   = (unsigned short*)(ws + 0x3202000);    // 16 MiB (B,C,N)
  unsigned short* aoT  = hT;                                   // reuse after h consumed

  const long NC = (long)N_ * C_;
  const int n_w = C_ * C_;

  gn_part<<<512, 256, 0, stream>>>(x, psum);
  conv_w<<<n_w / 256, 256, 0, stream>>>(qw, kw, vw, pw, qb, kb, wbf, qkb);
  gn_apply<<<dim3(N_ / 64, C_ / 64, B_), 256, 0, stream>>>(x, psum, nw, nb, hT);

  // fused Q+K: qkT[b][n][j] = sum_c hT[n][c] * wbf[j][c] + qkb[j]   (grid 16*8*8 = 1024)
  gemm_tn<true, false, false><<<dim3(1024), 256, 0, stream>>>(
      hT, wbf, qkb, nullptr, qkT, 1024, C_, NC, 0, (long)N_ * 1024);
  // v: vv[b][o][n] = sum_c vw[o][c] hT[n][c] + vb[o]                (grid 16*8*4 = 512)
  gemm_tn<true, true, false><<<dim3(512), 256, 0, stream>>>(
      wbf + 2 * n_w, hT, vb, nullptr, vv, N_, C_, 0, NC, NC);

  attn_kernel<<<dim3(512), 256, 0, stream>>>(qkT, vv, aoT);

  // p: out[b][o][n] = sum_c pw[o][c] ao[c][n] + pb[o] + x           (grid 16*8*4 = 512)
  gemm_tn<false, true, true><<<dim3(512), 256, 0, stream>>>(
      wbf + 3 * n_w, aoT, pb, x, d_out, N_, C_, 0, NC, NC);
}

// Round 12
// 143.300 us; speedup vs baseline: 1.6592x; 1.0037x over previous
//
#include <hip/hip_runtime.h>
#include <hip/hip_bf16.h>
#include <math.h>

#define B_    16
#define C_    512
#define N_    1024
#define G_    8
#define HEADS 4
#define CH    128
#define EPS   1e-5f

typedef __attribute__((ext_vector_type(8))) short short8;
typedef __attribute__((ext_vector_type(4))) float f32x4;
typedef __attribute__((ext_vector_type(16))) float f32x16;
typedef __attribute__((ext_vector_type(4))) int i32x4;

__device__ __forceinline__ unsigned short f2bf(float f) {
  union { float f; unsigned int i; } x; x.f = f;
  unsigned int r = x.i + 0x7FFFu + ((x.i >> 16) & 1u);
  return (unsigned short)(r >> 16);
}

// ---------------- GroupNorm partial sums: 4 chunks per (b,g), deterministic ----------------
__global__ __launch_bounds__(256) void gn_part(const float* __restrict__ x,
                                               float2* __restrict__ psum) {
  int blk = blockIdx.x;  // bg*4 + chunk, 0..511
  const float4* p4 = (const float4*)(x + (size_t)blk * 16384);
  float s = 0.f, ss = 0.f;
  for (int i = threadIdx.x; i < 4096; i += 256) {
    float4 v = p4[i];
    s  += v.x + v.y + v.z + v.w;
    ss += v.x * v.x + v.y * v.y + v.z * v.z + v.w * v.w;
  }
  for (int o = 32; o; o >>= 1) { s += __shfl_down(s, o); ss += __shfl_down(ss, o); }
  __shared__ float ls[4], lss[4];
  int wid = threadIdx.x >> 6, lane = threadIdx.x & 63;
  if (lane == 0) { ls[wid] = s; lss[wid] = ss; }
  __syncthreads();
  if (threadIdx.x == 0) {
    float2 r;
    r.x = (ls[0] + ls[1]) + (ls[2] + ls[3]);
    r.y = (lss[0] + lss[1]) + (lss[2] + lss[3]);
    psum[blk] = r;
  }
}

// ---------------- weight conversion fp32 -> bf16 + packed qk bias ----------------
__global__ __launch_bounds__(256) void conv_w(const float* __restrict__ q, const float* __restrict__ k,
                                              const float* __restrict__ v, const float* __restrict__ p,
                                              const float* __restrict__ qb, const float* __restrict__ kb,
                                              unsigned short* __restrict__ dst,
                                              float* __restrict__ qkb) {
  const int n = C_ * C_;
  int i = blockIdx.x * 256 + threadIdx.x;
  if (i < n) {
    dst[i]         = f2bf(q[i]);
    dst[n + i]     = f2bf(k[i]);
    dst[2 * n + i] = f2bf(v[i]);
    dst[3 * n + i] = f2bf(p[i]);
  }
  if (i < 1024) qkb[i] = (i < 512) ? qb[i] : kb[i - 512];
}

// ---------------- GroupNorm apply + transpose -> hT (B, N, C) bf16 ----------------
__global__ __launch_bounds__(256) void gn_apply(const float* __restrict__ x,
                                                const float2* __restrict__ psum,
                                                const float* __restrict__ gw,
                                                const float* __restrict__ gb,
                                                unsigned short* __restrict__ hT) {
  __shared__ float T[64][65];
  int b = blockIdx.z, c0 = blockIdx.y * 64, n0 = blockIdx.x * 64;
  int bg = b * G_ + (c0 >> 6);
  float2 p0 = psum[bg * 4 + 0], p1 = psum[bg * 4 + 1];
  float2 p2 = psum[bg * 4 + 2], p3 = psum[bg * 4 + 3];
  const float inv = 1.f / ((C_ / G_) * N_);
  float mean = ((p0.x + p1.x) + (p2.x + p3.x)) * inv;
  float var  = ((p0.y + p1.y) + (p2.y + p3.y)) * inv - mean * mean;
  float rstd = rsqrtf(var + EPS);
  int t = threadIdx.x;
  for (int it = 0; it < 4; it++) {
    int L = it * 256 + t;
    int cc = L >> 4, nf = L & 15;
    float4 v = *(const float4*)&x[((size_t)b * C_ + c0 + cc) * N_ + n0 + nf * 4];
    float sw = gw[c0 + cc] * rstd, sb = gb[c0 + cc] - mean * sw;
    T[cc][nf * 4 + 0] = v.x * sw + sb;
    T[cc][nf * 4 + 1] = v.y * sw + sb;
    T[cc][nf * 4 + 2] = v.z * sw + sb;
    T[cc][nf * 4 + 3] = v.w * sw + sb;
  }
  __syncthreads();
  for (int it = 0; it < 4; it++) {
    int L = it * 256 + t;
    int nn = L >> 4, cv = L & 15;
    ushort4 o;
    o.x = f2bf(T[cv * 4 + 0][nn]);
    o.y = f2bf(T[cv * 4 + 1][nn]);
    o.z = f2bf(T[cv * 4 + 2][nn]);
    o.w = f2bf(T[cv * 4 + 3][nn]);
    *(ushort4*)&hT[((size_t)b * N_ + n0 + nn) * C_ + c0 + cv * 4] = o;
  }
}

// ---------------- TN GEMM (m97-structure), XCD-grouped by batch ----------------
template <bool OUT_BF16, bool BIAS_I, bool RESID>
__global__ __launch_bounds__(256) void gemm_tn(const unsigned short* __restrict__ A,
                                               const unsigned short* __restrict__ Bt,
                                               const float* __restrict__ bias,
                                               const float* __restrict__ resid,
                                               void* __restrict__ out,
                                               int Ncols, int K,
                                               long aBS, long bBS, long oBS) {
  __shared__ __align__(16) unsigned short As[128 * 64];
  __shared__ __align__(16) unsigned short Bs[128 * 64];
  const int lin = blockIdx.x;
  const int b = (lin & 7) * 2 + ((lin >> 3) & 1);
  const int rest = lin >> 4;
  const int bx = rest & 7, by = rest >> 3;
  const int i0 = by * 128, j0 = bx * 128;
  const unsigned short* Ab = A + (size_t)b * aBS + (size_t)i0 * K;
  const unsigned short* Bb = Bt + (size_t)b * bBS + (size_t)j0 * K;
  const int t = threadIdx.x, w = t >> 6, l = t & 63;
  const int wi = (w >> 1) * 64, wj = (w & 1) * 64;
  const int lr = l & 15, lk = (l >> 4) * 8;
  const int srow = l >> 3, scol = (l & 7) * 8;

  f32x4 acc[4][4];
  const f32x4 zf = {0.f, 0.f, 0.f, 0.f};
#pragma unroll
  for (int m = 0; m < 4; m++)
#pragma unroll
    for (int n = 0; n < 4; n++) acc[m][n] = zf;

  for (int kt = 0; kt < K; kt += 64) {
    __syncthreads();
#pragma unroll
    for (int i = 0; i < 4; i++) {
      int seg = w * 4 + i;
      int row = seg * 8 + srow;
      __builtin_amdgcn_global_load_lds(
          (const __attribute__((address_space(1))) void*)&Ab[(size_t)row * K + kt + scol],
          (__attribute__((address_space(3))) void*)&As[seg * 512], 16, 0, 0);
      __builtin_amdgcn_global_load_lds(
          (const __attribute__((address_space(1))) void*)&Bb[(size_t)row * K + kt + scol],
          (__attribute__((address_space(3))) void*)&Bs[seg * 512], 16, 0, 0);
    }
    __syncthreads();
#pragma unroll
    for (int ks = 0; ks < 64; ks += 32) {
      short8 af[4], bf[4];
#pragma unroll
      for (int m = 0; m < 4; m++) af[m] = *(const short8*)&As[(wi + m * 16 + lr) * 64 + ks + lk];
#pragma unroll
      for (int n = 0; n < 4; n++) bf[n] = *(const short8*)&Bs[(wj + n * 16 + lr) * 64 + ks + lk];
#pragma unroll
      for (int m = 0; m < 4; m++)
#pragma unroll
        for (int n = 0; n < 4; n++)
          acc[m][n] = __builtin_amdgcn_mfma_f32_16x16x32_bf16(af[m], bf[n], acc[m][n], 0, 0, 0);
    }
  }

  int rbase = (l >> 4) * 4;
#pragma unroll
  for (int m = 0; m < 4; m++) {
    int ig = i0 + wi + m * 16 + rbase;
#pragma unroll
    for (int n = 0; n < 4; n++) {
      int jg = j0 + wj + n * 16 + lr;
#pragma unroll
      for (int r = 0; r < 4; r++) {
        float vv = acc[m][n][r];
        vv += BIAS_I ? bias[ig + r] : bias[jg];
        size_t oidx = (size_t)b * oBS + (size_t)(ig + r) * Ncols + jg;
        if (RESID) vv += resid[oidx];
        if (OUT_BF16) ((unsigned short*)out)[oidx] = f2bf(vv);
        else ((float*)out)[oidx] = vv;
      }
    }
  }
}

// ---------------- fused flash attention: r6 structure (proven) + hoisted stage pointers ----
// qkT: (B, N, 1024) bf16 (q cols 0..511, k cols 512..1023); v: (B, C, N) bf16; out aoT: (B, N, C) bf16
__global__ __launch_bounds__(256, 2) void attn_kernel(const unsigned short* __restrict__ qkT,
                                                      const unsigned short* __restrict__ v,
                                                      unsigned short* __restrict__ aoT) {
  // K: 2 bufs [64 kv][128 c] (16 KiB each); V: 3 bufs [128 c][64 kv] (16 KiB each) => 80 KiB
  __shared__ __align__(16) unsigned short Ks[2][64 * 128];
  __shared__ __align__(16) unsigned short Vs[3][128 * 64];
  const int t = threadIdx.x, w = t >> 6, l = t & 63;
  const int h = l >> 5, l31 = l & 31, l7 = l & 7;
  const int lin = blockIdx.x;
  const int bh = (lin & 7) * 8 + ((lin >> 3) & 7);  // XCD-grouped: all q-tiles of bh on one XCD
  const int qt = lin >> 6;
  const int b = bh >> 2, hd = bh & 3, c0h = hd * CH;
  const int qg = qt * 128 + w * 32 + l31;
  const float sc2 = 0.08838834764831845f * 1.4426950408889634f;  // scale * log2(e)
  const float THRRAW = 11.5f / sc2;                              // defer-max threshold

  // Q fragments (MFMA B-operand)
  short8 qf[8];
  const unsigned short* qrow = qkT + ((size_t)b * N_ + qg) * 1024 + c0h;
#pragma unroll
  for (int kc = 0; kc < 8; kc++) qf[kc] = *(const short8*)&qrow[kc * 16 + h * 8];

  f32x16 o[4];
#pragma unroll
  for (int ct = 0; ct < 4; ct++) o[ct] = (f32x16)(0.f);
  float m = -INFINITY, lsum = 0.f;

  // hoisted pre-swizzled staging source pointers (advance one 64-kv tile per stage call)
  const unsigned short* ksrcp[4];
  const unsigned short* vsrcp[4];
#pragma unroll
  for (int i = 0; i < 4; i++) {
    int seg = w * 4 + i;               // 0..15
    int rowK = seg * 4 + (l >> 4);     // 0..63
    int gcK = (l & 15) ^ (rowK & 7);   // proven pair (r6/r9)
    ksrcp[i] = qkT + ((size_t)b * N_ + rowK) * 1024 + 512 + c0h + gcK * 8;
    int rowV = seg * 8 + (l >> 3);     // 0..127
    int gcV = (l & 7) ^ (rowV & 7);    // proven pair (r6/r9)
    vsrcp[i] = v + ((size_t)b * C_ + c0h + rowV) * N_ + gcV * 8;
  }
  auto stage = [&](int kbuf, int vbuf) {
#pragma unroll
    for (int i = 0; i < 4; i++) {
      int seg = w * 4 + i;
      __builtin_amdgcn_global_load_lds((const __attribute__((address_space(1))) void*)ksrcp[i],
                                       (__attribute__((address_space(3))) void*)&Ks[kbuf][seg * 512],
                                       16, 0, 0);
      ksrcp[i] += (size_t)64 * 1024;
      __builtin_amdgcn_global_load_lds((const __attribute__((address_space(1))) void*)vsrcp[i],
                                       (__attribute__((address_space(3))) void*)&Vs[vbuf][seg * 512],
                                       16, 0, 0);
      vsrcp[i] += 64;
    }
  };

  // prologue: tiles 0 and 1
  stage(0, 0);
  stage(1, 1);
  __syncthreads();  // tiles 0,1 resident

  // QK^T(0): S^T[kv][q] = sum_c K[kv][c] * Q[q][c]
  f32x16 st0 = (f32x16)(0.f), st1 = (f32x16)(0.f);
  {
    const unsigned short* KsB = &Ks[0][0];
#pragma unroll
    for (int kc = 0; kc < 8; kc++) {
      short8 kf0 = *(const short8*)&KsB[l31 * 128 + (((2 * kc + h) ^ l7) * 8)];
      short8 kf1 = *(const short8*)&KsB[(32 + l31) * 128 + (((2 * kc + h) ^ l7) * 8)];
      st0 = __builtin_amdgcn_mfma_f32_32x32x16_bf16(kf0, qf[kc], st0, 0, 0, 0);
      st1 = __builtin_amdgcn_mfma_f32_32x32x16_bf16(kf1, qf[kc], st1, 0, 0, 0);
    }
  }
  __syncthreads();  // all waves done reading Ks[0] (tt=0 restages it)

  for (int tt = 0; tt < 16; tt++) {
    // stage tile tt+2: K into Ks[tt&1] (tile tt read last iter), V into Vs[(tt+2)%3]
    if (tt < 14) stage(tt & 1, (tt + 2) % 3);

    // ---- softmax(tt) on st0/st1 ----
    float tr[16];
#pragma unroll
    for (int r = 0; r < 16; r++) tr[r] = fmaxf(st0[r], st1[r]);
#pragma unroll
    for (int s = 8; s >= 1; s >>= 1)
#pragma unroll
      for (int r = 0; r < s; r++) tr[r] = fmaxf(tr[r], tr[r + s]);
    float pmax = fmaxf(tr[0], __shfl_xor(tr[0], 32));

    bool skip = __all(pmax <= m + THRRAW);
    float mnew = skip ? m : fmaxf(m, pmax);
    float alpha = skip ? 1.f : exp2f((m - mnew) * sc2);
    float mb = mnew * sc2;
    m = mnew;

    float psg[4];
    short8 pf[4];
#pragma unroll
    for (int g = 0; g < 4; g++) {
      const int e0 = (g & 1) * 8;
      float p0, p1, p2, p3, p4, p5, p6, p7;
      if (g < 2) {
        p0 = exp2f(fmaf(st0[e0 + 0], sc2, -mb)); p1 = exp2f(fmaf(st0[e0 + 1], sc2, -mb));
        p2 = exp2f(fmaf(st0[e0 + 2], sc2, -mb)); p3 = exp2f(fmaf(st0[e0 + 3], sc2, -mb));
        p4 = exp2f(fmaf(st0[e0 + 4], sc2, -mb)); p5 = exp2f(fmaf(st0[e0 + 5], sc2, -mb));
        p6 = exp2f(fmaf(st0[e0 + 6], sc2, -mb)); p7 = exp2f(fmaf(st0[e0 + 7], sc2, -mb));
      } else {
        p0 = exp2f(fmaf(st1[e0 + 0], sc2, -mb)); p1 = exp2f(fmaf(st1[e0 + 1], sc2, -mb));
        p2 = exp2f(fmaf(st1[e0 + 2], sc2, -mb)); p3 = exp2f(fmaf(st1[e0 + 3], sc2, -mb));
        p4 = exp2f(fmaf(st1[e0 + 4], sc2, -mb)); p5 = exp2f(fmaf(st1[e0 + 5], sc2, -mb));
        p6 = exp2f(fmaf(st1[e0 + 6], sc2, -mb)); p7 = exp2f(fmaf(st1[e0 + 7], sc2, -mb));
      }
      psg[g] = ((p0 + p1) + (p2 + p3)) + ((p4 + p5) + (p6 + p7));
      unsigned int x, x2, y, y2;
      asm("v_cvt_pk_bf16_f32 %0, %1, %2" : "=v"(x)  : "v"(p0), "v"(p1));
      asm("v_cvt_pk_bf16_f32 %0, %1, %2" : "=v"(x2) : "v"(p2), "v"(p3));
      asm("v_cvt_pk_bf16_f32 %0, %1, %2" : "=v"(y)  : "v"(p4), "v"(p5));
      asm("v_cvt_pk_bf16_f32 %0, %1, %2" : "=v"(y2) : "v"(p6), "v"(p7));
      asm("v_permlane32_swap_b32 %0, %1" : "+v"(x), "+v"(y));
      asm("v_permlane32_swap_b32 %0, %1" : "+v"(x2), "+v"(y2));
      i32x4 pwv = {(int)x, (int)x2, (int)y, (int)y2};
      pf[g] = __builtin_bit_cast(short8, pwv);
    }
    float ps = (psg[0] + psg[1]) + (psg[2] + psg[3]);
    ps += __shfl_xor(ps, 32);
    lsum = lsum * alpha + ps;

    if (!skip) {
#pragma unroll
      for (int ct = 0; ct < 4; ct++)
#pragma unroll
        for (int r = 0; r < 16; r++) o[ct][r] *= alpha;
    }

    // ---- MFMA cluster: QK^T(tt+1) interleaved with PV(tt) ----
    const unsigned short* VsB = &Vs[tt % 3][0];
    __builtin_amdgcn_s_setprio(1);
    if (tt < 15) {
      const unsigned short* KsN = &Ks[(tt + 1) & 1][0];
      f32x16 nst0 = (f32x16)(0.f), nst1 = (f32x16)(0.f);
#pragma unroll
      for (int kc = 0; kc < 8; kc++) {
        short8 kf0 = *(const short8*)&KsN[l31 * 128 + (((2 * kc + h) ^ l7) * 8)];
        short8 kf1 = *(const short8*)&KsN[(32 + l31) * 128 + (((2 * kc + h) ^ l7) * 8)];
        nst0 = __builtin_amdgcn_mfma_f32_32x32x16_bf16(kf0, qf[kc], nst0, 0, 0, 0);
        nst1 = __builtin_amdgcn_mfma_f32_32x32x16_bf16(kf1, qf[kc], nst1, 0, 0, 0);
        {  // two PV MFMAs per kc: p = 2*kc, 2*kc+1; ct = p&3, g = p>>2
          int p = 2 * kc;
          int ct = p & 3, g = p >> 2;
          short8 vf = *(const short8*)&VsB[(ct * 32 + l31) * 64 + (((2 * g + h) ^ l7) * 8)];
          o[ct] = __builtin_amdgcn_mfma_f32_32x32x16_bf16(vf, pf[g], o[ct], 0, 0, 0);
          p = 2 * kc + 1;
          ct = p & 3; g = p >> 2;
          vf = *(const short8*)&VsB[(ct * 32 + l31) * 64 + (((2 * g + h) ^ l7) * 8)];
          o[ct] = __builtin_amdgcn_mfma_f32_32x32x16_bf16(vf, pf[g], o[ct], 0, 0, 0);
        }
      }
      __builtin_amdgcn_s_setprio(0);
      __syncthreads();  // all reads done; stage(tt+2) landed
      st0 = nst0; st1 = nst1;
    } else {
#pragma unroll
      for (int p = 0; p < 16; p++) {
        int ct = p & 3, g = p >> 2;
        short8 vf = *(const short8*)&VsB[(ct * 32 + l31) * 64 + (((2 * g + h) ^ l7) * 8)];
        o[ct] = __builtin_amdgcn_mfma_f32_32x32x16_bf16(vf, pf[g], o[ct], 0, 0, 0);
      }
      __builtin_amdgcn_s_setprio(0);
    }
  }

  float rn = 1.f / lsum;
  unsigned short* orow = aoT + ((size_t)b * N_ + qg) * C_ + c0h;
#pragma unroll
  for (int ct = 0; ct < 4; ct++)
#pragma unroll
    for (int u = 0; u < 4; u++) {
      ushort4 ov;
      ov.x = f2bf(o[ct][u * 4 + 0] * rn);
      ov.y = f2bf(o[ct][u * 4 + 1] * rn);
      ov.z = f2bf(o[ct][u * 4 + 2] * rn);
      ov.w = f2bf(o[ct][u * 4 + 3] * rn);
      *(ushort4*)&orow[ct * 32 + u * 8 + h * 4] = ov;
    }
}

extern "C" void kernel_launch(void* const* d_in, const int* in_sizes, int n_in,
                              void* d_out, int out_size, void* d_ws, size_t ws_size,
                              hipStream_t stream) {
  const float* x  = (const float*)d_in[0];
  const float* nw = (const float*)d_in[1];
  const float* nb = (const float*)d_in[2];
  const float* qw = (const float*)d_in[3];
  const float* qb = (const float*)d_in[4];
  const float* kw = (const float*)d_in[5];
  const float* kb = (const float*)d_in[6];
  const float* vw = (const float*)d_in[7];
  const float* vb = (const float*)d_in[8];
  const float* pw = (const float*)d_in[9];
  const float* pb = (const float*)d_in[10];

  char* ws = (char*)d_ws;
  unsigned short* wbf  = (unsigned short*)ws;                  // 4 x 512*512 bf16 (q,k,v,p)
  float2*         psum = (float2*)(ws + 0x200000);             // 512 float2 partial sums
  float*          qkb  = (float*)(ws + 0x201000);              // 1024 floats packed q,k bias
  unsigned short* hT   = (unsigned short*)(ws + 0x202000);     // 16 MiB (B,N,C)
  unsigned short* qkT  = (unsigned short*)(ws + 0x1202000);    // 32 MiB (B,N,1024)
  unsigned short* vv   = (unsigned short*)(ws + 0x3202000);    // 16 MiB (B,C,N)
  unsigned short* aoT  = hT;                                   // reuse after h consumed

  const long NC = (long)N_ * C_;
  const int n_w = C_ * C_;

  gn_part<<<512, 256, 0, stream>>>(x, psum);
  conv_w<<<n_w / 256, 256, 0, stream>>>(qw, kw, vw, pw, qb, kb, wbf, qkb);
  gn_apply<<<dim3(N_ / 64, C_ / 64, B_), 256, 0, stream>>>(x, psum, nw, nb, hT);

  // fused Q+K: qkT[b][n][j] = sum_c hT[n][c] * wbf[j][c] + qkb[j]   (grid 16*8*8 = 1024)
  gemm_tn<true, false, false><<<dim3(1024), 256, 0, stream>>>(
      hT, wbf, qkb, nullptr, qkT, 1024, C_, NC, 0, (long)N_ * 1024);
  // v: vv[b][o][n] = sum_c vw[o][c] hT[n][c] + vb[o]                (grid 16*8*4 = 512)
  gemm_tn<true, true, false><<<dim3(512), 256, 0, stream>>>(
      wbf + 2 * n_w, hT, vb, nullptr, vv, N_, C_, 0, NC, NC);

  attn_kernel<<<dim3(512), 256, 0, stream>>>(qkT, vv, aoT);

  // p: out[b][o][n] = sum_c pw[o][c] ao[c][n] + pb[o] + x           (grid 16*8*4 = 512)
  gemm_tn<false, true, true><<<dim3(512), 256, 0, stream>>>(
      wbf + 3 * n_w, aoT, pb, x, d_out, N_, C_, 0, NC, NC);
}

// Round 13
// 137.673 us; speedup vs baseline: 1.7270x; 1.0409x over previous
//
#include <hip/hip_runtime.h>
#include <hip/hip_bf16.h>
#include <math.h>

#define B_    16
#define C_    512
#define N_    1024
#define G_    8
#define HEADS 4
#define CH    128
#define EPS   1e-5f

typedef __attribute__((ext_vector_type(8))) short short8;
typedef __attribute__((ext_vector_type(4))) float f32x4;
typedef __attribute__((ext_vector_type(16))) float f32x16;
typedef __attribute__((ext_vector_type(4))) int i32x4;

__device__ __forceinline__ unsigned short f2bf(float f) {
  union { float f; unsigned int i; } x; x.f = f;
  unsigned int r = x.i + 0x7FFFu + ((x.i >> 16) & 1u);
  return (unsigned short)(r >> 16);
}

// ---------------- fused: GroupNorm partial sums (blocks 0..511) + weight conv (512..1535) ----
__global__ __launch_bounds__(256) void gn_part_conv(const float* __restrict__ x,
                                                    float2* __restrict__ psum,
                                                    const float* __restrict__ qw, const float* __restrict__ kw,
                                                    const float* __restrict__ vw, const float* __restrict__ pw,
                                                    const float* __restrict__ qb, const float* __restrict__ kb,
                                                    unsigned short* __restrict__ wbf,
                                                    float* __restrict__ qkb) {
  int blk = blockIdx.x;
  if (blk < 512) {
    const float4* p4 = (const float4*)(x + (size_t)blk * 16384);
    float s = 0.f, ss = 0.f;
    for (int i = threadIdx.x; i < 4096; i += 256) {
      float4 v = p4[i];
      s  += v.x + v.y + v.z + v.w;
      ss += v.x * v.x + v.y * v.y + v.z * v.z + v.w * v.w;
    }
    for (int o = 32; o; o >>= 1) { s += __shfl_down(s, o); ss += __shfl_down(ss, o); }
    __shared__ float ls[4], lss[4];
    int wid = threadIdx.x >> 6, lane = threadIdx.x & 63;
    if (lane == 0) { ls[wid] = s; lss[wid] = ss; }
    __syncthreads();
    if (threadIdx.x == 0) {
      float2 r;
      r.x = (ls[0] + ls[1]) + (ls[2] + ls[3]);
      r.y = (lss[0] + lss[1]) + (lss[2] + lss[3]);
      psum[blk] = r;
    }
  } else {
    const int n = C_ * C_;
    int i = (blk - 512) * 256 + threadIdx.x;  // 0..262143 == n-1
    wbf[i]         = f2bf(qw[i]);
    wbf[n + i]     = f2bf(kw[i]);
    wbf[2 * n + i] = f2bf(vw[i]);
    wbf[3 * n + i] = f2bf(pw[i]);
    if (i < 1024) qkb[i] = (i < 512) ? qb[i] : kb[i - 512];
  }
}

// ---------------- GroupNorm apply + transpose -> hT (B, N, C) bf16 ----------------
__global__ __launch_bounds__(256) void gn_apply(const float* __restrict__ x,
                                                const float2* __restrict__ psum,
                                                const float* __restrict__ gw,
                                                const float* __restrict__ gb,
                                                unsigned short* __restrict__ hT) {
  __shared__ float T[64][65];
  int b = blockIdx.z, c0 = blockIdx.y * 64, n0 = blockIdx.x * 64;
  int bg = b * G_ + (c0 >> 6);
  float2 p0 = psum[bg * 4 + 0], p1 = psum[bg * 4 + 1];
  float2 p2 = psum[bg * 4 + 2], p3 = psum[bg * 4 + 3];
  const float inv = 1.f / ((C_ / G_) * N_);
  float mean = ((p0.x + p1.x) + (p2.x + p3.x)) * inv;
  float var  = ((p0.y + p1.y) + (p2.y + p3.y)) * inv - mean * mean;
  float rstd = rsqrtf(var + EPS);
  int t = threadIdx.x;
  for (int it = 0; it < 4; it++) {
    int L = it * 256 + t;
    int cc = L >> 4, nf = L & 15;
    float4 v = *(const float4*)&x[((size_t)b * C_ + c0 + cc) * N_ + n0 + nf * 4];
    float sw = gw[c0 + cc] * rstd, sb = gb[c0 + cc] - mean * sw;
    T[cc][nf * 4 + 0] = v.x * sw + sb;
    T[cc][nf * 4 + 1] = v.y * sw + sb;
    T[cc][nf * 4 + 2] = v.z * sw + sb;
    T[cc][nf * 4 + 3] = v.w * sw + sb;
  }
  __syncthreads();
  for (int it = 0; it < 4; it++) {
    int L = it * 256 + t;
    int nn = L >> 4, cv = L & 15;
    ushort4 o;
    o.x = f2bf(T[cv * 4 + 0][nn]);
    o.y = f2bf(T[cv * 4 + 1][nn]);
    o.z = f2bf(T[cv * 4 + 2][nn]);
    o.w = f2bf(T[cv * 4 + 3][nn]);
    *(ushort4*)&hT[((size_t)b * N_ + n0 + nn) * C_ + c0 + cv * 4] = o;
  }
}

// ---------------- fused QK + V GEMM, one dispatch (1536 blocks), m97 structure ----------------
// lin < 1024: QK block — out qkT[b][n][j] = sum_c hT[n][c]*wbf[j][c] + qkb[j]
// lin >= 1024: V block — out vv[b][o][n] = sum_c vw[o][c]*hT[n][c] + vb[o]
__global__ __launch_bounds__(256) void gemm_qkv(const unsigned short* __restrict__ hT,
                                                const unsigned short* __restrict__ wbf,
                                                const float* __restrict__ qkb,
                                                const float* __restrict__ vb,
                                                unsigned short* __restrict__ qkT,
                                                unsigned short* __restrict__ vv) {
  __shared__ __align__(16) unsigned short As[128 * 64];
  __shared__ __align__(16) unsigned short Bs[128 * 64];
  const int lin0 = blockIdx.x;
  const bool isV = lin0 >= 1024;
  const int lin = isV ? lin0 - 1024 : lin0;
  const int b = (lin & 7) * 2 + ((lin >> 3) & 1);
  const int rest = lin >> 4;
  const int bx = rest & 7, by = rest >> 3;
  const int i0 = by * 128, j0 = bx * 128;
  const long NC = (long)N_ * C_;
  const int n_w = C_ * C_;
  const unsigned short* Ab;
  const unsigned short* Bb;
  const float* bias;
  unsigned short* out;
  long oBS;
  if (isV) {
    Ab = wbf + 2 * n_w + (size_t)i0 * C_;
    Bb = hT + (size_t)b * NC + (size_t)j0 * C_;
    bias = vb; out = vv; oBS = NC;
  } else {
    Ab = hT + (size_t)b * NC + (size_t)i0 * C_;
    Bb = wbf + (size_t)j0 * C_;
    bias = qkb; out = qkT; oBS = (long)N_ * 1024;
  }
  const int t = threadIdx.x, w = t >> 6, l = t & 63;
  const int wi = (w >> 1) * 64, wj = (w & 1) * 64;
  const int lr = l & 15, lk = (l >> 4) * 8;
  const int srow = l >> 3, scol = (l & 7) * 8;

  f32x4 acc[4][4];
  const f32x4 zf = {0.f, 0.f, 0.f, 0.f};
#pragma unroll
  for (int m = 0; m < 4; m++)
#pragma unroll
    for (int n = 0; n < 4; n++) acc[m][n] = zf;

  for (int kt = 0; kt < C_; kt += 64) {
    __syncthreads();
#pragma unroll
    for (int i = 0; i < 4; i++) {
      int seg = w * 4 + i;
      int row = seg * 8 + srow;
      __builtin_amdgcn_global_load_lds(
          (const __attribute__((address_space(1))) void*)&Ab[(size_t)row * C_ + kt + scol],
          (__attribute__((address_space(3))) void*)&As[seg * 512], 16, 0, 0);
      __builtin_amdgcn_global_load_lds(
          (const __attribute__((address_space(1))) void*)&Bb[(size_t)row * C_ + kt + scol],
          (__attribute__((address_space(3))) void*)&Bs[seg * 512], 16, 0, 0);
    }
    __syncthreads();
#pragma unroll
    for (int ks = 0; ks < 64; ks += 32) {
      short8 af[4], bf[4];
#pragma unroll
      for (int m = 0; m < 4; m++) af[m] = *(const short8*)&As[(wi + m * 16 + lr) * 64 + ks + lk];
#pragma unroll
      for (int n = 0; n < 4; n++) bf[n] = *(const short8*)&Bs[(wj + n * 16 + lr) * 64 + ks + lk];
#pragma unroll
      for (int m = 0; m < 4; m++)
#pragma unroll
        for (int n = 0; n < 4; n++)
          acc[m][n] = __builtin_amdgcn_mfma_f32_16x16x32_bf16(af[m], bf[n], acc[m][n], 0, 0, 0);
    }
  }

  int rbase = (l >> 4) * 4;
#pragma unroll
  for (int m = 0; m < 4; m++) {
    int ig = i0 + wi + m * 16 + rbase;
#pragma unroll
    for (int n = 0; n < 4; n++) {
      int jg = j0 + wj + n * 16 + lr;
#pragma unroll
      for (int r = 0; r < 4; r++) {
        float vvv = acc[m][n][r];
        vvv += isV ? bias[ig + r] : bias[jg];
        size_t oidx = (size_t)b * oBS + (size_t)(ig + r) * 1024 + jg;
        out[oidx] = f2bf(vvv);
      }
    }
  }
}

// ---------------- P GEMM (m97-structure), fp32 out + residual, XCD-grouped by batch ----------
__global__ __launch_bounds__(256) void gemm_p(const unsigned short* __restrict__ A,
                                              const unsigned short* __restrict__ Bt,
                                              const float* __restrict__ bias,
                                              const float* __restrict__ resid,
                                              float* __restrict__ out) {
  __shared__ __align__(16) unsigned short As[128 * 64];
  __shared__ __align__(16) unsigned short Bs[128 * 64];
  const int lin = blockIdx.x;
  const int b = (lin & 7) * 2 + ((lin >> 3) & 1);
  const int rest = lin >> 4;
  const int bx = rest & 7, by = rest >> 3;
  const int i0 = by * 128, j0 = bx * 128;
  const long NC = (long)N_ * C_;
  const unsigned short* Ab = A + (size_t)i0 * C_;
  const unsigned short* Bb = Bt + (size_t)b * NC + (size_t)j0 * C_;
  const int t = threadIdx.x, w = t >> 6, l = t & 63;
  const int wi = (w >> 1) * 64, wj = (w & 1) * 64;
  const int lr = l & 15, lk = (l >> 4) * 8;
  const int srow = l >> 3, scol = (l & 7) * 8;

  f32x4 acc[4][4];
  const f32x4 zf = {0.f, 0.f, 0.f, 0.f};
#pragma unroll
  for (int m = 0; m < 4; m++)
#pragma unroll
    for (int n = 0; n < 4; n++) acc[m][n] = zf;

  for (int kt = 0; kt < C_; kt += 64) {
    __syncthreads();
#pragma unroll
    for (int i = 0; i < 4; i++) {
      int seg = w * 4 + i;
      int row = seg * 8 + srow;
      __builtin_amdgcn_global_load_lds(
          (const __attribute__((address_space(1))) void*)&Ab[(size_t)row * C_ + kt + scol],
          (__attribute__((address_space(3))) void*)&As[seg * 512], 16, 0, 0);
      __builtin_amdgcn_global_load_lds(
          (const __attribute__((address_space(1))) void*)&Bb[(size_t)row * C_ + kt + scol],
          (__attribute__((address_space(3))) void*)&Bs[seg * 512], 16, 0, 0);
    }
    __syncthreads();
#pragma unroll
    for (int ks = 0; ks < 64; ks += 32) {
      short8 af[4], bf[4];
#pragma unroll
      for (int m = 0; m < 4; m++) af[m] = *(const short8*)&As[(wi + m * 16 + lr) * 64 + ks + lk];
#pragma unroll
      for (int n = 0; n < 4; n++) bf[n] = *(const short8*)&Bs[(wj + n * 16 + lr) * 64 + ks + lk];
#pragma unroll
      for (int m = 0; m < 4; m++)
#pragma unroll
        for (int n = 0; n < 4; n++)
          acc[m][n] = __builtin_amdgcn_mfma_f32_16x16x32_bf16(af[m], bf[n], acc[m][n], 0, 0, 0);
    }
  }

  int rbase = (l >> 4) * 4;
#pragma unroll
  for (int m = 0; m < 4; m++) {
    int ig = i0 + wi + m * 16 + rbase;
#pragma unroll
    for (int n = 0; n < 4; n++) {
      int jg = j0 + wj + n * 16 + lr;
#pragma unroll
      for (int r = 0; r < 4; r++) {
        float vv = acc[m][n][r] + bias[ig + r];
        size_t oidx = (size_t)b * NC + (size_t)(ig + r) * N_ + jg;
        out[oidx] = vv + resid[oidx];
      }
    }
  }
}

// ---------------- fused flash attention: r12 structure (verbatim, proven 64 us) ----------------
__global__ __launch_bounds__(256, 2) void attn_kernel(const unsigned short* __restrict__ qkT,
                                                      const unsigned short* __restrict__ v,
                                                      unsigned short* __restrict__ aoT) {
  __shared__ __align__(16) unsigned short Ks[2][64 * 128];
  __shared__ __align__(16) unsigned short Vs[3][128 * 64];
  const int t = threadIdx.x, w = t >> 6, l = t & 63;
  const int h = l >> 5, l31 = l & 31, l7 = l & 7;
  const int lin = blockIdx.x;
  const int bh = (lin & 7) * 8 + ((lin >> 3) & 7);
  const int qt = lin >> 6;
  const int b = bh >> 2, hd = bh & 3, c0h = hd * CH;
  const int qg = qt * 128 + w * 32 + l31;
  const float sc2 = 0.08838834764831845f * 1.4426950408889634f;
  const float THRRAW = 11.5f / sc2;

  short8 qf[8];
  const unsigned short* qrow = qkT + ((size_t)b * N_ + qg) * 1024 + c0h;
#pragma unroll
  for (int kc = 0; kc < 8; kc++) qf[kc] = *(const short8*)&qrow[kc * 16 + h * 8];

  f32x16 o[4];
#pragma unroll
  for (int ct = 0; ct < 4; ct++) o[ct] = (f32x16)(0.f);
  float m = -INFINITY, lsum = 0.f;

  const unsigned short* ksrcp[4];
  const unsigned short* vsrcp[4];
#pragma unroll
  for (int i = 0; i < 4; i++) {
    int seg = w * 4 + i;
    int rowK = seg * 4 + (l >> 4);
    int gcK = (l & 15) ^ (rowK & 7);
    ksrcp[i] = qkT + ((size_t)b * N_ + rowK) * 1024 + 512 + c0h + gcK * 8;
    int rowV = seg * 8 + (l >> 3);
    int gcV = (l & 7) ^ (rowV & 7);
    vsrcp[i] = v + ((size_t)b * C_ + c0h + rowV) * N_ + gcV * 8;
  }
  auto stage = [&](int kbuf, int vbuf) {
#pragma unroll
    for (int i = 0; i < 4; i++) {
      int seg = w * 4 + i;
      __builtin_amdgcn_global_load_lds((const __attribute__((address_space(1))) void*)ksrcp[i],
                                       (__attribute__((address_space(3))) void*)&Ks[kbuf][seg * 512],
                                       16, 0, 0);
      ksrcp[i] += (size_t)64 * 1024;
      __builtin_amdgcn_global_load_lds((const __attribute__((address_space(1))) void*)vsrcp[i],
                                       (__attribute__((address_space(3))) void*)&Vs[vbuf][seg * 512],
                                       16, 0, 0);
      vsrcp[i] += 64;
    }
  };

  stage(0, 0);
  stage(1, 1);
  __syncthreads();

  f32x16 st0 = (f32x16)(0.f), st1 = (f32x16)(0.f);
  {
    const unsigned short* KsB = &Ks[0][0];
#pragma unroll
    for (int kc = 0; kc < 8; kc++) {
      short8 kf0 = *(const short8*)&KsB[l31 * 128 + (((2 * kc + h) ^ l7) * 8)];
      short8 kf1 = *(const short8*)&KsB[(32 + l31) * 128 + (((2 * kc + h) ^ l7) * 8)];
      st0 = __builtin_amdgcn_mfma_f32_32x32x16_bf16(kf0, qf[kc], st0, 0, 0, 0);
      st1 = __builtin_amdgcn_mfma_f32_32x32x16_bf16(kf1, qf[kc], st1, 0, 0, 0);
    }
  }
  __syncthreads();

  for (int tt = 0; tt < 16; tt++) {
    if (tt < 14) stage(tt & 1, (tt + 2) % 3);

    float tr[16];
#pragma unroll
    for (int r = 0; r < 16; r++) tr[r] = fmaxf(st0[r], st1[r]);
#pragma unroll
    for (int s = 8; s >= 1; s >>= 1)
#pragma unroll
      for (int r = 0; r < s; r++) tr[r] = fmaxf(tr[r], tr[r + s]);
    float pmax = fmaxf(tr[0], __shfl_xor(tr[0], 32));

    bool skip = __all(pmax <= m + THRRAW);
    float mnew = skip ? m : fmaxf(m, pmax);
    float alpha = skip ? 1.f : exp2f((m - mnew) * sc2);
    float mb = mnew * sc2;
    m = mnew;

    float psg[4];
    short8 pf[4];
#pragma unroll
    for (int g = 0; g < 4; g++) {
      const int e0 = (g & 1) * 8;
      float p0, p1, p2, p3, p4, p5, p6, p7;
      if (g < 2) {
        p0 = exp2f(fmaf(st0[e0 + 0], sc2, -mb)); p1 = exp2f(fmaf(st0[e0 + 1], sc2, -mb));
        p2 = exp2f(fmaf(st0[e0 + 2], sc2, -mb)); p3 = exp2f(fmaf(st0[e0 + 3], sc2, -mb));
        p4 = exp2f(fmaf(st0[e0 + 4], sc2, -mb)); p5 = exp2f(fmaf(st0[e0 + 5], sc2, -mb));
        p6 = exp2f(fmaf(st0[e0 + 6], sc2, -mb)); p7 = exp2f(fmaf(st0[e0 + 7], sc2, -mb));
      } else {
        p0 = exp2f(fmaf(st1[e0 + 0], sc2, -mb)); p1 = exp2f(fmaf(st1[e0 + 1], sc2, -mb));
        p2 = exp2f(fmaf(st1[e0 + 2], sc2, -mb)); p3 = exp2f(fmaf(st1[e0 + 3], sc2, -mb));
        p4 = exp2f(fmaf(st1[e0 + 4], sc2, -mb)); p5 = exp2f(fmaf(st1[e0 + 5], sc2, -mb));
        p6 = exp2f(fmaf(st1[e0 + 6], sc2, -mb)); p7 = exp2f(fmaf(st1[e0 + 7], sc2, -mb));
      }
      psg[g] = ((p0 + p1) + (p2 + p3)) + ((p4 + p5) + (p6 + p7));
      unsigned int x, x2, y, y2;
      asm("v_cvt_pk_bf16_f32 %0, %1, %2" : "=v"(x)  : "v"(p0), "v"(p1));
      asm("v_cvt_pk_bf16_f32 %0, %1, %2" : "=v"(x2) : "v"(p2), "v"(p3));
      asm("v_cvt_pk_bf16_f32 %0, %1, %2" : "=v"(y)  : "v"(p4), "v"(p5));
      asm("v_cvt_pk_bf16_f32 %0, %1, %2" : "=v"(y2) : "v"(p6), "v"(p7));
      asm("v_permlane32_swap_b32 %0, %1" : "+v"(x), "+v"(y));
      asm("v_permlane32_swap_b32 %0, %1" : "+v"(x2), "+v"(y2));
      i32x4 pwv = {(int)x, (int)x2, (int)y, (int)y2};
      pf[g] = __builtin_bit_cast(short8, pwv);
    }
    float ps = (psg[0] + psg[1]) + (psg[2] + psg[3]);
    ps += __shfl_xor(ps, 32);
    lsum = lsum * alpha + ps;

    if (!skip) {
#pragma unroll
      for (int ct = 0; ct < 4; ct++)
#pragma unroll
        for (int r = 0; r < 16; r++) o[ct][r] *= alpha;
    }

    const unsigned short* VsB = &Vs[tt % 3][0];
    __builtin_amdgcn_s_setprio(1);
    if (tt < 15) {
      const unsigned short* KsN = &Ks[(tt + 1) & 1][0];
      f32x16 nst0 = (f32x16)(0.f), nst1 = (f32x16)(0.f);
#pragma unroll
      for (int kc = 0; kc < 8; kc++) {
        short8 kf0 = *(const short8*)&KsN[l31 * 128 + (((2 * kc + h) ^ l7) * 8)];
        short8 kf1 = *(const short8*)&KsN[(32 + l31) * 128 + (((2 * kc + h) ^ l7) * 8)];
        nst0 = __builtin_amdgcn_mfma_f32_32x32x16_bf16(kf0, qf[kc], nst0, 0, 0, 0);
        nst1 = __builtin_amdgcn_mfma_f32_32x32x16_bf16(kf1, qf[kc], nst1, 0, 0, 0);
        {
          int p = 2 * kc;
          int ct = p & 3, g = p >> 2;
          short8 vf = *(const short8*)&VsB[(ct * 32 + l31) * 64 + (((2 * g + h) ^ l7) * 8)];
          o[ct] = __builtin_amdgcn_mfma_f32_32x32x16_bf16(vf, pf[g], o[ct], 0, 0, 0);
          p = 2 * kc + 1;
          ct = p & 3; g = p >> 2;
          vf = *(const short8*)&VsB[(ct * 32 + l31) * 64 + (((2 * g + h) ^ l7) * 8)];
          o[ct] = __builtin_amdgcn_mfma_f32_32x32x16_bf16(vf, pf[g], o[ct], 0, 0, 0);
        }
      }
      __builtin_amdgcn_s_setprio(0);
      __syncthreads();
      st0 = nst0; st1 = nst1;
    } else {
#pragma unroll
      for (int p = 0; p < 16; p++) {
        int ct = p & 3, g = p >> 2;
        short8 vf = *(const short8*)&VsB[(ct * 32 + l31) * 64 + (((2 * g + h) ^ l7) * 8)];
        o[ct] = __builtin_amdgcn_mfma_f32_32x32x16_bf16(vf, pf[g], o[ct], 0, 0, 0);
      }
      __builtin_amdgcn_s_setprio(0);
    }
  }

  float rn = 1.f / lsum;
  unsigned short* orow = aoT + ((size_t)b * N_ + qg) * C_ + c0h;
#pragma unroll
  for (int ct = 0; ct < 4; ct++)
#pragma unroll
    for (int u = 0; u < 4; u++) {
      ushort4 ov;
      ov.x = f2bf(o[ct][u * 4 + 0] * rn);
      ov.y = f2bf(o[ct][u * 4 + 1] * rn);
      ov.z = f2bf(o[ct][u * 4 + 2] * rn);
      ov.w = f2bf(o[ct][u * 4 + 3] * rn);
      *(ushort4*)&orow[ct * 32 + u * 8 + h * 4] = ov;
    }
}

extern "C" void kernel_launch(void* const* d_in, const int* in_sizes, int n_in,
                              void* d_out, int out_size, void* d_ws, size_t ws_size,
                              hipStream_t stream) {
  const float* x  = (const float*)d_in[0];
  const float* nw = (const float*)d_in[1];
  const float* nb = (const float*)d_in[2];
  const float* qw = (const float*)d_in[3];
  const float* qb = (const float*)d_in[4];
  const float* kw = (const float*)d_in[5];
  const float* kb = (const float*)d_in[6];
  const float* vw = (const float*)d_in[7];
  const float* vb = (const float*)d_in[8];
  const float* pw = (const float*)d_in[9];
  const float* pb = (const float*)d_in[10];

  char* ws = (char*)d_ws;
  unsigned short* wbf  = (unsigned short*)ws;                  // 4 x 512*512 bf16 (q,k,v,p)
  float2*         psum = (float2*)(ws + 0x200000);             // 512 float2 partial sums
  float*          qkb  = (float*)(ws + 0x201000);              // 1024 floats packed q,k bias
  unsigned short* hT   = (unsigned short*)(ws + 0x202000);     // 16 MiB (B,N,C)
  unsigned short* qkT  = (unsigned short*)(ws + 0x1202000);    // 32 MiB (B,N,1024)
  unsigned short* vv   = (unsigned short*)(ws + 0x3202000);    // 16 MiB (B,C,N)
  unsigned short* aoT  = hT;                                   // reuse after h consumed

  const int n_w = C_ * C_;

  gn_part_conv<<<dim3(1536), 256, 0, stream>>>(x, psum, qw, kw, vw, pw, qb, kb, wbf, qkb);
  gn_apply<<<dim3(N_ / 64, C_ / 64, B_), 256, 0, stream>>>(x, psum, nw, nb, hT);

  // fused QK (1024 blocks) + V (512 blocks)
  gemm_qkv<<<dim3(1536), 256, 0, stream>>>(hT, wbf, qkb, vb, qkT, vv);

  attn_kernel<<<dim3(512), 256, 0, stream>>>(qkT, vv, aoT);

  // p: out[b][o][n] = sum_c pw[o][c] ao[c][n] + pb[o] + x
  gemm_p<<<dim3(512), 256, 0, stream>>>(wbf + 3 * n_w, aoT, pb, x, (float*)d_out);
}